// Round 1
// baseline (1611.658 us; speedup 1.0000x reference)
//
#include <hip/hip_runtime.h>
#include <hip/hip_bf16.h>

// Fenwick TreeLSTM, N=32768, D=256.
// All matmuls are (M x 512) @ (512 x 1280) done with bf16 16x16x32 MFMA,
// fp32 accumulate; c-path stays fp32. Phase-2 is compacted to the 16384
// rows per iteration that actually have bit k set.

typedef unsigned short u16;
typedef unsigned int u32;
using short8  = __attribute__((ext_vector_type(8))) short;
using float4v = __attribute__((ext_vector_type(4))) float;

// ---- workspace layout (bytes) ----
// WmT  @ 0         : 1280x512 bf16  (1,310,720)
// WsT  @ 1310720   : 1280x512 bf16  (1,310,720)
// h0b  @ 2621440   : 32768x256 bf16 (16,777,216)   level-0 h in bf16
// hlv  @ 19398656  : levels 1..15 h bf16 (32767 rows used of 32768)
// clv  @ 36175872  : levels 1..15 c fp32 (33,554,432)
// sth  @ 69730304  : state_h bf16 (16,777,216)
// z    @ 86507520  : 8192x1280 fp32 chunk buffer (41,943,040)
// total ~128.5 MB

__device__ __forceinline__ u16 f2bf(float f) {
  u32 u = __float_as_uint(f);
  u = (u + 0x7FFFu + ((u >> 16) & 1u)) >> 16;
  return (u16)u;
}
__device__ __forceinline__ float bf2f(u16 h) {
  return __uint_as_float(((u32)h) << 16);
}
__device__ __forceinline__ float sigf(float x) { return 1.0f / (1.0f + __expf(-x)); }
__device__ __forceinline__ float tanhfast(float x) {
  return 2.0f / (1.0f + __expf(-2.0f * x)) - 1.0f;
}

__device__ __forceinline__ void async16(const void* g, void* l) {
  __builtin_amdgcn_global_load_lds((const __attribute__((address_space(1))) void*)g,
                                   (__attribute__((address_space(3))) void*)l,
                                   16, 0, 0);
}

// A-row gather: row i of A = concat(hl(256 bf16), hr(256 bf16)).
// mode 0: phase-1 level k, children = rows 2i, 2i+1 of level k-1.
// mode 1: phase-2 iter k, hl = state_h[t-1], hr = node at level k.
__device__ __forceinline__ void row_srcs(int mode, int k, int row,
                                         const u16* h0b, const u16* hlv, const u16* sth,
                                         const u16*& pL, const u16*& pR) {
  if (mode == 0) {
    const u16* pb = (k == 1) ? h0b : (hlv + (size_t)(32768 - (1 << (17 - k))) * 256);
    pL = pb + (size_t)(2 * row) * 256;
    pR = pb + (size_t)(2 * row + 1) * 256;
  } else {
    int t = ((row >> k) << (k + 1)) | (1 << k) | (row & ((1 << k) - 1));
    pL = sth + (size_t)(t - 1) * 256;
    int idx = (t >> (k + 1)) * 2;
    pR = hlv + (size_t)((32768 - (1 << (16 - k))) + idx) * 256;
  }
}

// z[Mc x 1280] = gathered A[Mc x 512] @ W[512 x 1280]  (bias added in cell kernels)
// 128x128 tile, BK=32, 4 waves, each wave 4x4 of 16x16x32 bf16 MFMA.
__global__ __launch_bounds__(256) void gemm_z(
    int mode, int k, int row0, int Mc,
    const u16* __restrict__ WT, float* __restrict__ z,
    const u16* __restrict__ h0b, const u16* __restrict__ hlv,
    const u16* __restrict__ sth)
{
  __shared__ __align__(16) u16 smem[8192];  // A: u16[0,4096)  B: u16[4096,8192)
  const int tid  = threadIdx.x;
  const int lane = tid & 63;
  const int w    = tid >> 6;
  const int wm   = w >> 1, wn = w & 1;
  const int bm   = blockIdx.x, bn = blockIdx.y;

  // staging descriptors: flat slot f -> (tile row f>>2, 16B seg f&3)
  const int f0 = w * 128 + lane;
  const int f1 = f0 + 64;
  int rl0 = bm * 128 + (f0 >> 2); if (rl0 > Mc - 1) rl0 = Mc - 1;
  int rl1 = bm * 128 + (f1 >> 2); if (rl1 > Mc - 1) rl1 = Mc - 1;
  const u16 *p0L, *p0R, *p1L, *p1R;
  row_srcs(mode, k, row0 + rl0, h0b, hlv, sth, p0L, p0R);
  row_srcs(mode, k, row0 + rl1, h0b, hlv, sth, p1L, p1R);
  const int sa0 = (f0 & 3) * 8, sa1 = (f1 & 3) * 8;
  const u16* pB0 = WT + (size_t)(bn * 128 + (f0 >> 2)) * 512 + sa0;
  const u16* pB1 = WT + (size_t)(bn * 128 + (f1 >> 2)) * 512 + sa1;

  // wave-uniform LDS chunk bases (global_load_lds writes base + lane*16)
  u16* ldsA0 = smem + (w * 2 + 0) * 512;
  u16* ldsA1 = smem + (w * 2 + 1) * 512;
  u16* ldsB0 = smem + 4096 + (w * 2 + 0) * 512;
  u16* ldsB1 = smem + 4096 + (w * 2 + 1) * 512;

  float4v acc[4][4];
#pragma unroll
  for (int i = 0; i < 4; ++i)
#pragma unroll
    for (int j = 0; j < 4; ++j) acc[i][j] = (float4v){0.f, 0.f, 0.f, 0.f};

  const int mrow = lane & 15;   // A row / B col within 16-tile
  const int kg   = lane >> 4;   // k-group
  const u16* aBase = smem + (wm * 64 + mrow) * 32 + kg * 8;
  const u16* bBase = smem + 4096 + (wn * 64 + mrow) * 32 + kg * 8;

  for (int kk = 0; kk < 16; ++kk) {
    // K 0..255 comes from L source, 256..511 from R source
    const u16* s0 = (kk < 8) ? (p0L + sa0 + kk * 32) : (p0R + sa0 + (kk - 8) * 32);
    const u16* s1 = (kk < 8) ? (p1L + sa1 + kk * 32) : (p1R + sa1 + (kk - 8) * 32);
    async16(s0, ldsA0);
    async16(s1, ldsA1);
    async16(pB0 + kk * 32, ldsB0);
    async16(pB1 + kk * 32, ldsB1);
    __syncthreads();
    short8 af[4], bfr[4];
#pragma unroll
    for (int mt = 0; mt < 4; ++mt) af[mt]  = *(const short8*)(aBase + mt * 512);
#pragma unroll
    for (int nt = 0; nt < 4; ++nt) bfr[nt] = *(const short8*)(bBase + nt * 512);
#pragma unroll
    for (int mt = 0; mt < 4; ++mt)
#pragma unroll
      for (int nt = 0; nt < 4; ++nt)
        acc[mt][nt] = __builtin_amdgcn_mfma_f32_16x16x32_bf16(af[mt], bfr[nt], acc[mt][nt], 0, 0, 0);
    __syncthreads();
  }

  // C/D layout: col = lane&15, row = (lane>>4)*4 + r
#pragma unroll
  for (int mt = 0; mt < 4; ++mt) {
    const int r0 = bm * 128 + wm * 64 + mt * 16 + kg * 4;
#pragma unroll
    for (int nt = 0; nt < 4; ++nt) {
      const int col = bn * 128 + wn * 64 + nt * 16 + mrow;
#pragma unroll
      for (int r = 0; r < 4; ++r) {
        const int row = r0 + r;
        if (row < Mc) z[(size_t)row * 1280 + col] = acc[mt][nt][r];
      }
    }
  }
}

// phase-1 cell: level-k h (bf16) and c (fp32) from z + parent c's
__global__ __launch_bounds__(256) void cell_phase1(
    int row0, const float* __restrict__ z, const float* __restrict__ b,
    const float* __restrict__ cpar, float* __restrict__ cout, u16* __restrict__ hout)
{
  const int rl = blockIdx.x;
  const int rg = row0 + rl;
  const int d  = threadIdx.x;
  const float* zr = z + (size_t)rl * 1280;
  const float zi  = zr[d]        + b[d];
  const float zo  = zr[256 + d]  + b[256 + d];
  const float zu  = zr[512 + d]  + b[512 + d];
  const float zfl = zr[768 + d]  + b[768 + d];
  const float zfr = zr[1024 + d] + b[1024 + d];
  const float cl = cpar[(size_t)(2 * rg) * 256 + d];
  const float cr = cpar[(size_t)(2 * rg + 1) * 256 + d];
  const float c = sigf(zi) * tanhfast(zu) + sigf(zfl) * cl + sigf(zfr) * cr;
  const float h = sigf(zo) * tanhfast(c);
  cout[(size_t)rg * 256 + d] = c;
  hout[(size_t)rg * 256 + d] = f2bf(h);
}

// phase-2 cell for iteration k; rows are the i-th t with bit k set.
// first-touch rows (low k bits of t all zero) copy the node instead.
__global__ __launch_bounds__(256) void cell_phase2(
    int k, int row0, const float* __restrict__ z, const float* __restrict__ b,
    const u16* __restrict__ hlv, const float* __restrict__ clv,
    float* __restrict__ out, u16* __restrict__ sth)
{
  const int rl = blockIdx.x;
  const int i  = row0 + rl;
  const int d  = threadIdx.x;
  const int t  = ((i >> k) << (k + 1)) | (1 << k) | (i & ((1 << k) - 1));
  const int lk = 32768 - (1 << (16 - k));
  const int idx = (t >> (k + 1)) * 2;
  const float cr = clv[(size_t)(lk + idx) * 256 + d];
  float h, c;
  if ((i & ((1 << k) - 1)) == 0) {
    h = bf2f(hlv[(size_t)(lk + idx) * 256 + d]);
    c = cr;
  } else {
    const float* zr = z + (size_t)rl * 1280;
    const float zi  = zr[d]        + b[d];
    const float zo  = zr[256 + d]  + b[256 + d];
    const float zu  = zr[512 + d]  + b[512 + d];
    const float zfl = zr[768 + d]  + b[768 + d];
    const float zfr = zr[1024 + d] + b[1024 + d];
    const float cl = out[(size_t)(t - 1) * 512 + 256 + d];
    c = sigf(zi) * tanhfast(zu) + sigf(zfl) * cl + sigf(zfr) * cr;
    h = sigf(zo) * tanhfast(c);
  }
  out[(size_t)(t - 1) * 512 + d] = h;
  out[(size_t)(t - 1) * 512 + 256 + d] = c;
  sth[(size_t)(t - 1) * 256 + d] = f2bf(h);
}

// k=0: all odd t are first-touch copies of the leaves
__global__ __launch_bounds__(256) void copy_k0(
    const float* __restrict__ h_bot, const float* __restrict__ c_bot,
    float* __restrict__ out, u16* __restrict__ sth)
{
  const int i = blockIdx.x;          // 0..16383
  const int d = threadIdx.x;
  const int t = 2 * i + 1;
  const float h = h_bot[(size_t)(t - 1) * 256 + d];
  const float c = c_bot[(size_t)(t - 1) * 256 + d];
  out[(size_t)(t - 1) * 512 + d] = h;
  out[(size_t)(t - 1) * 512 + 256 + d] = c;
  sth[(size_t)(t - 1) * 256 + d] = f2bf(h);
}

// k=15: t=32768 is a first-touch copy of level-15's single node (row 32766)
__global__ __launch_bounds__(256) void copy_k15(
    const u16* __restrict__ hlv, const float* __restrict__ clv, float* __restrict__ out)
{
  const int d = threadIdx.x;
  out[(size_t)32767 * 512 + d] = bf2f(hlv[(size_t)32766 * 256 + d]);
  out[(size_t)32767 * 512 + 256 + d] = clv[(size_t)32766 * 256 + d];
}

// W (512x1280 fp32) -> W^T (1280x512 bf16), n-major rows for b128 frag reads
__global__ __launch_bounds__(256) void transpose_w(
    const float* __restrict__ W, u16* __restrict__ WT)
{
  const int n = blockIdx.x;          // 0..1279
  const int tid = threadIdx.x;       // 0..255
  WT[(size_t)n * 512 + tid]       = f2bf(W[(size_t)tid * 1280 + n]);
  WT[(size_t)n * 512 + tid + 256] = f2bf(W[(size_t)(tid + 256) * 1280 + n]);
}

__global__ __launch_bounds__(256) void cast_h0(
    const float* __restrict__ h, u16* __restrict__ h0b)
{
  const size_t i = (size_t)blockIdx.x * 256 + threadIdx.x;
  h0b[i] = f2bf(h[i]);
}

extern "C" void kernel_launch(void* const* d_in, const int* in_sizes, int n_in,
                              void* d_out, int out_size, void* d_ws, size_t ws_size,
                              hipStream_t stream) {
  const float* h_bot = (const float*)d_in[0];
  const float* c_bot = (const float*)d_in[1];
  const float* Wm    = (const float*)d_in[2];
  const float* bmv   = (const float*)d_in[3];
  const float* Wsu   = (const float*)d_in[4];
  const float* bsv   = (const float*)d_in[5];
  float* out = (float*)d_out;
  char* ws = (char*)d_ws;

  u16*   WmT = (u16*)(ws + 0);
  u16*   WsT = (u16*)(ws + 1310720);
  u16*   h0b = (u16*)(ws + 2621440);
  u16*   hlv = (u16*)(ws + 19398656);
  float* clv = (float*)(ws + 36175872);
  u16*   sth = (u16*)(ws + 69730304);
  float* z   = (float*)(ws + 86507520);

  transpose_w<<<1280, 256, 0, stream>>>(Wm, WmT);
  transpose_w<<<1280, 256, 0, stream>>>(Wsu, WsT);
  cast_h0<<<32768, 256, 0, stream>>>(h_bot, h0b);

  // ---- phase 1: build tree levels ----
  for (int k = 1; k <= 15; ++k) {
    const int M = 32768 >> k;
    const int nch = (M > 8192) ? (M / 8192) : 1;   // chunk only level 1
    const int Mc = M / nch;
    const float* cpar = (k == 1) ? c_bot : (clv + (size_t)(32768 - (1 << (17 - k))) * 256);
    float* cout = clv + (size_t)(32768 - (1 << (16 - k))) * 256;
    u16*   hout = hlv + (size_t)(32768 - (1 << (16 - k))) * 256;
    for (int ch = 0; ch < nch; ++ch) {
      const int row0 = ch * Mc;
      dim3 grid((Mc + 127) / 128, 10);
      gemm_z<<<grid, 256, 0, stream>>>(0, k, row0, Mc, WmT, z, h0b, hlv, sth);
      cell_phase1<<<Mc, 256, 0, stream>>>(row0, z, bmv, cpar, cout, hout);
    }
  }

  // ---- phase 2: Fenwick accumulation ----
  copy_k0<<<16384, 256, 0, stream>>>(h_bot, c_bot, out, sth);
  for (int k = 1; k <= 14; ++k) {
    for (int ch = 0; ch < 2; ++ch) {
      const int row0 = ch * 8192;
      dim3 grid(64, 10);
      gemm_z<<<grid, 256, 0, stream>>>(1, k, row0, 8192, WsT, z, h0b, hlv, sth);
      cell_phase2<<<8192, 256, 0, stream>>>(k, row0, z, bsv, hlv, clv, out, sth);
    }
  }
  copy_k15<<<1, 256, 0, stream>>>(hlv, clv, out);
}

// Round 4
// 1240.705 us; speedup vs baseline: 1.2990x; 1.2990x over previous
//
#include <hip/hip_runtime.h>
#include <hip/hip_bf16.h>

// Fenwick TreeLSTM, N=32768, D=256 — fused GEMM+cell, async LDS staging.
// (M x 512) @ (512 x 1280) bf16 MFMA, fp32 accumulate; LSTM-cell epilogue
// fused via gate-permuted W^T: n' = b*160 + g*32 + dl <-> col g*256 + b*32 + dl.
// Phase-2 state_h double-buffered (sth read / sthN written) + merge kernel
// between iterations to kill the cross-block RAW race on state rows.

typedef unsigned short u16;
typedef unsigned int u32;
using short8  = __attribute__((ext_vector_type(8))) short;
using float4v = __attribute__((ext_vector_type(4))) float;

// ---- workspace layout (bytes) ----
// WmT  @ 0         : 1280x512 bf16 gate-permuted (1,310,720)
// WsT  @ 1310720   : 1280x512 bf16 gate-permuted (1,310,720)
// h0b  @ 2621440   : 32768x256 bf16 (16,777,216)
// hlv  @ 19398656  : levels 1..15 h bf16 (16,777,216)
// clv  @ 36175872  : levels 1..15 c fp32 (33,554,432)
// sth  @ 69730304  : state_h bf16, stable copy (16,777,216)
// sthN @ 86507520  : state_h bf16, iteration-k writes (16,777,216)
// total ~103.3 MB (round-1 footprint of 128.5 MB ran fine)

__device__ __forceinline__ u16 f2bf(float f) {
  u32 u = __float_as_uint(f);
  u = (u + 0x7FFFu + ((u >> 16) & 1u)) >> 16;
  return (u16)u;
}
__device__ __forceinline__ float bf2f(u16 h) {
  return __uint_as_float(((u32)h) << 16);
}
__device__ __forceinline__ float sigf(float x) { return 1.0f / (1.0f + __expf(-x)); }
__device__ __forceinline__ float tanhfast(float x) {
  return 2.0f / (1.0f + __expf(-2.0f * x)) - 1.0f;
}

__device__ __forceinline__ void async16(const void* g, void* l) {
  __builtin_amdgcn_global_load_lds((const __attribute__((address_space(1))) void*)g,
                                   (__attribute__((address_space(3))) void*)l,
                                   16, 0, 0);
}

// A-row gather: row i of A = concat(hl(256 bf16), hr(256 bf16)).
__device__ __forceinline__ void row_srcs(int mode, int k, int row,
                                         const u16* h0b, const u16* hlv, const u16* sth,
                                         const u16*& pL, const u16*& pR) {
  if (mode == 0) {
    const u16* pb = (k == 1) ? h0b : (hlv + (size_t)(32768 - (1 << (17 - k))) * 256);
    pL = pb + (size_t)(2 * row) * 256;
    pR = pb + (size_t)(2 * row + 1) * 256;
  } else {
    int t = ((row >> k) << (k + 1)) | (1 << k) | (row & ((1 << k) - 1));
    pL = sth + (size_t)(t - 1) * 256;
    int idx = (t >> (k + 1)) * 2;
    pR = hlv + (size_t)((32768 - (1 << (16 - k))) + idx) * 256;
  }
}

// Fused GEMM + LSTM cell.
// Block tile: 128 rows x 160 cols (5 gates x 32 d), BK=32, 16 K-steps.
// 4 waves as 2(m) x 2(n): wave = 64 rows x 16 d's, acc[4 m-tiles][5 gates].
__global__ __launch_bounds__(256) void gemm_cell(
    int mode, int k, int Mc,
    const u16* WT, const float* bias,
    const u16* h0b, const u16* hlv, const u16* sth_in,
    const float* cpar, float* cout, u16* hout,
    const float* clv, float* out, u16* sth_out)
{
  __shared__ __align__(16) u16 smem[9216];  // A u16[0,4096)  B u16[4096,9216)
  const int tid  = threadIdx.x;
  const int lane = tid & 63;
  const int w    = tid >> 6;
  const int wm   = w >> 1, wn = w & 1;
  const int bm   = blockIdx.x, bn = blockIdx.y;

  // ---- A staging: 512 slots (row = f>>2, 16B seg = f&3), 2 rounds ----
  const int f0 = w * 128 + lane;
  const int f1 = f0 + 64;
  int rl0 = bm * 128 + (f0 >> 2); if (rl0 > Mc - 1) rl0 = Mc - 1;
  int rl1 = bm * 128 + (f1 >> 2); if (rl1 > Mc - 1) rl1 = Mc - 1;
  const u16 *p0L, *p0R, *p1L, *p1R;
  row_srcs(mode, k, rl0, h0b, hlv, sth_in, p0L, p0R);
  row_srcs(mode, k, rl1, h0b, hlv, sth_in, p1L, p1R);
  const int sa0 = (f0 & 3) * 8, sa1 = (f1 & 3) * 8;
  u16* ldsA0 = smem + (w * 2 + 0) * 512;
  u16* ldsA1 = smem + (w * 2 + 1) * 512;

  // ---- B staging: 640 slots over 10 chunks of 16 rows; 3 rounds ----
  const int ch0 = 0 * 4 + w, ch1 = 1 * 4 + w, ch2 = 2 * 4 + w;  // ch2 valid for w<2
  const u16* pB0 = WT + (size_t)(bn * 160 + ch0 * 16 + (lane >> 2)) * 512 + (lane & 3) * 8;
  const u16* pB1 = WT + (size_t)(bn * 160 + ch1 * 16 + (lane >> 2)) * 512 + (lane & 3) * 8;
  const u16* pB2 = (ch2 < 10)
      ? WT + (size_t)(bn * 160 + ch2 * 16 + (lane >> 2)) * 512 + (lane & 3) * 8
      : pB0;
  u16* ldsB0 = smem + 4096 + ch0 * 512;
  u16* ldsB1 = smem + 4096 + ch1 * 512;
  u16* ldsB2 = smem + 4096 + (ch2 < 10 ? ch2 : 0) * 512;

  float4v acc[4][5];
#pragma unroll
  for (int i = 0; i < 4; ++i)
#pragma unroll
    for (int j = 0; j < 5; ++j) acc[i][j] = (float4v){0.f, 0.f, 0.f, 0.f};

  const int mrow = lane & 15;
  const int kg   = lane >> 4;
  const u16* aBase = smem + (wm * 64 + mrow) * 32 + kg * 8;
  const u16* bBase = smem + 4096 + (wn * 16 + mrow) * 32 + kg * 8;  // + g*1024

  for (int kk = 0; kk < 16; ++kk) {
    const u16* s0 = (kk < 8) ? (p0L + sa0 + kk * 32) : (p0R + sa0 + (kk - 8) * 32);
    const u16* s1 = (kk < 8) ? (p1L + sa1 + kk * 32) : (p1R + sa1 + (kk - 8) * 32);
    async16(s0, ldsA0);
    async16(s1, ldsA1);
    async16(pB0 + kk * 32, ldsB0);
    async16(pB1 + kk * 32, ldsB1);
    if (ch2 < 10) async16(pB2 + kk * 32, ldsB2);
    __syncthreads();
    short8 af[4], bfr[5];
#pragma unroll
    for (int mt = 0; mt < 4; ++mt) af[mt]  = *(const short8*)(aBase + mt * 512);
#pragma unroll
    for (int g = 0; g < 5; ++g)   bfr[g]  = *(const short8*)(bBase + g * 1024);
#pragma unroll
    for (int mt = 0; mt < 4; ++mt)
#pragma unroll
      for (int g = 0; g < 5; ++g)
        acc[mt][g] = __builtin_amdgcn_mfma_f32_16x16x32_bf16(af[mt], bfr[g], acc[mt][g], 0, 0, 0);
    __syncthreads();
  }

  // ---- fused cell epilogue ----
  // lane owns d = bn*32 + wn*16 + mrow; rows r0..r0+3 per m-tile.
  const int d = bn * 32 + wn * 16 + mrow;
  const float bi  = bias[d];
  const float bo  = bias[256 + d];
  const float bu  = bias[512 + d];
  const float bfl = bias[768 + d];
  const float bfr2= bias[1024 + d];

#pragma unroll
  for (int mt = 0; mt < 4; ++mt) {
    const int r0 = bm * 128 + wm * 64 + mt * 16 + kg * 4;
#pragma unroll
    for (int r = 0; r < 4; ++r) {
      const int row = r0 + r;
      if (row >= Mc) continue;
      const float zi  = acc[mt][0][r] + bi;
      const float zo  = acc[mt][1][r] + bo;
      const float zu  = acc[mt][2][r] + bu;
      const float zfl = acc[mt][3][r] + bfl;
      const float zfr = acc[mt][4][r] + bfr2;
      if (mode == 0) {
        const float cl = cpar[(size_t)(2 * row) * 256 + d];
        const float cr = cpar[(size_t)(2 * row + 1) * 256 + d];
        const float c = sigf(zi) * tanhfast(zu) + sigf(zfl) * cl + sigf(zfr) * cr;
        const float h = sigf(zo) * tanhfast(c);
        cout[(size_t)row * 256 + d] = c;
        hout[(size_t)row * 256 + d] = f2bf(h);
      } else {
        const int i  = row;
        const int t  = ((i >> k) << (k + 1)) | (1 << k) | (i & ((1 << k) - 1));
        const int lk = 32768 - (1 << (16 - k));
        const int idx = (t >> (k + 1)) * 2;
        const float cr = clv[(size_t)(lk + idx) * 256 + d];
        float h, c;
        if ((i & ((1 << k) - 1)) == 0) {
          h = bf2f(hlv[(size_t)(lk + idx) * 256 + d]);
          c = cr;
        } else {
          const float cl = out[(size_t)(t - 1) * 512 + 256 + d];
          c = sigf(zi) * tanhfast(zu) + sigf(zfl) * cl + sigf(zfr) * cr;
          h = sigf(zo) * tanhfast(c);
        }
        out[(size_t)(t - 1) * 512 + d] = h;
        out[(size_t)(t - 1) * 512 + 256 + d] = c;
        sth_out[(size_t)(t - 1) * 256 + d] = f2bf(h);
      }
    }
  }
}

// merge iteration-k state rows: sth[t-1] <- sthN[t-1] for all 16384 t's of iter k
__global__ __launch_bounds__(256) void merge_sth(
    int k, const u16* src, u16* dst)
{
  const int idx = blockIdx.x * 256 + threadIdx.x;   // 0..524287
  const int i = idx >> 5;
  const int s = (idx & 31) * 8;
  const int t = ((i >> k) << (k + 1)) | (1 << k) | (i & ((1 << k) - 1));
  *(short8*)(dst + (size_t)(t - 1) * 256 + s) = *(const short8*)(src + (size_t)(t - 1) * 256 + s);
}

// k=0: all odd t are first-touch copies of the leaves
__global__ __launch_bounds__(256) void copy_k0(
    const float* __restrict__ h_bot, const float* __restrict__ c_bot,
    float* __restrict__ out, u16* __restrict__ sth)
{
  const int i = blockIdx.x;          // 0..16383
  const int d = threadIdx.x;
  const int t = 2 * i + 1;
  const float h = h_bot[(size_t)(t - 1) * 256 + d];
  const float c = c_bot[(size_t)(t - 1) * 256 + d];
  out[(size_t)(t - 1) * 512 + d] = h;
  out[(size_t)(t - 1) * 512 + 256 + d] = c;
  sth[(size_t)(t - 1) * 256 + d] = f2bf(h);
}

// k=15: t=32768 copies level-15's single node (global row 32766)
__global__ __launch_bounds__(256) void copy_k15(
    const u16* __restrict__ hlv, const float* __restrict__ clv, float* __restrict__ out)
{
  const int d = threadIdx.x;
  out[(size_t)32767 * 512 + d] = bf2f(hlv[(size_t)32766 * 256 + d]);
  out[(size_t)32767 * 512 + 256 + d] = clv[(size_t)32766 * 256 + d];
}

// W (512x1280 fp32) -> gate-permuted W^T (1280x512 bf16).
// Output row n': b=n'/160, r=n'%160, g=r/32, dl=r%32 -> src col g*256 + b*32 + dl.
__global__ __launch_bounds__(256) void transpose_w(
    const float* __restrict__ W, u16* __restrict__ WT)
{
  const int n = blockIdx.x;          // 0..1279 (permuted)
  const int b = n / 160, r = n % 160;
  const int g = r / 32,  dl = r % 32;
  const int col = g * 256 + b * 32 + dl;
  const int tid = threadIdx.x;       // 0..255
  WT[(size_t)n * 512 + tid]       = f2bf(W[(size_t)tid * 1280 + col]);
  WT[(size_t)n * 512 + tid + 256] = f2bf(W[(size_t)(tid + 256) * 1280 + col]);
}

__global__ __launch_bounds__(256) void cast_h0(
    const float* __restrict__ h, u16* __restrict__ h0b)
{
  const size_t i = (size_t)blockIdx.x * 256 + threadIdx.x;
  h0b[i] = f2bf(h[i]);
}

extern "C" void kernel_launch(void* const* d_in, const int* in_sizes, int n_in,
                              void* d_out, int out_size, void* d_ws, size_t ws_size,
                              hipStream_t stream) {
  const float* h_bot = (const float*)d_in[0];
  const float* c_bot = (const float*)d_in[1];
  const float* Wm    = (const float*)d_in[2];
  const float* bmv   = (const float*)d_in[3];
  const float* Wsu   = (const float*)d_in[4];
  const float* bsv   = (const float*)d_in[5];
  float* out = (float*)d_out;
  char* ws = (char*)d_ws;

  u16*   WmT  = (u16*)(ws + 0);
  u16*   WsT  = (u16*)(ws + 1310720);
  u16*   h0b  = (u16*)(ws + 2621440);
  u16*   hlv  = (u16*)(ws + 19398656);
  float* clv  = (float*)(ws + 36175872);
  u16*   sth  = (u16*)(ws + 69730304);
  u16*   sthN = (u16*)(ws + 86507520);

  transpose_w<<<1280, 256, 0, stream>>>(Wm, WmT);
  transpose_w<<<1280, 256, 0, stream>>>(Wsu, WsT);
  cast_h0<<<32768, 256, 0, stream>>>(h_bot, h0b);

  // ---- phase 1: build tree levels (fused; race-free, disjoint levels) ----
  for (int kl = 1; kl <= 15; ++kl) {
    const int M = 32768 >> kl;
    const float* cpar = (kl == 1) ? c_bot : (clv + (size_t)(32768 - (1 << (17 - kl))) * 256);
    float* cout = clv + (size_t)(32768 - (1 << (16 - kl))) * 256;
    u16*   hout = hlv + (size_t)(32768 - (1 << (16 - kl))) * 256;
    dim3 grid((M + 127) / 128, 8);
    gemm_cell<<<grid, 256, 0, stream>>>(0, kl, M, WmT, bmv, h0b, hlv, sth,
                                        cpar, cout, hout, clv, out, sthN);
  }

  // ---- phase 2: Fenwick accumulation (fused; sth stable, sthN written) ----
  copy_k0<<<16384, 256, 0, stream>>>(h_bot, c_bot, out, sth);
  for (int kl = 1; kl <= 14; ++kl) {
    dim3 grid(128, 8);
    gemm_cell<<<grid, 256, 0, stream>>>(1, kl, 16384, WsT, bsv, h0b, hlv, sth,
                                        nullptr, nullptr, nullptr, clv, out, sthN);
    merge_sth<<<2048, 256, 0, stream>>>(kl, sthN, sth);
  }
  copy_k15<<<1, 256, 0, stream>>>(hlv, clv, out);
}